// Round 6
// baseline (100.789 us; speedup 1.0000x reference)
//
#include <hip/hip_runtime.h>
#include <hip/hip_bf16.h>
#include <math.h>

#define DEV static __device__ __forceinline__

typedef unsigned short u16;
typedef unsigned int u32;
typedef __attribute__((ext_vector_type(4))) float f32x4;
typedef __attribute__((ext_vector_type(16))) float f32x16;
typedef __attribute__((ext_vector_type(8))) __bf16 bf16x8;
typedef __attribute__((ext_vector_type(4))) u16 u16x4;
typedef __attribute__((ext_vector_type(4))) u32 u32x4;

// float -> bf16 bits, round-to-nearest-even
DEV u16 f2bf(float f) {
  unsigned u = __float_as_uint(f);
  u += 0x7fffu + ((u >> 16) & 1u);
  return (u16)(u >> 16);
}
DEV float bf2f(u16 x) { return __uint_as_float((u32)x << 16); }

// single-instruction v_exp_f32
DEV float fexp2(float x) { return __builtin_amdgcn_exp2f(x); }

DEV u32 cvt_pk_bf16(float lo, float hi) {
  u32 r;
  asm("v_cvt_pk_bf16_f32 %0, %1, %2" : "=v"(r) : "v"(lo), "v"(hi));
  return r;
}

// v_permlane32_swap_b32: a' = {a.lo, b.lo}, b' = {a.hi, b.hi}
DEV void perm32swap(u32& a, u32& b) {
  asm("v_permlane32_swap_b32 %0, %1" : "+v"(a), "+v"(b));
}

DEV void gl2lds16(const void* g, void* l) {
  __builtin_amdgcn_global_load_lds(
      (const __attribute__((address_space(1))) void*)g,
      (__attribute__((address_space(3))) void*)l, 16, 0, 0);
}

// Stage RPW rows (per wave) x 64 bf16 cols from global into linear LDS [rows][64]
// with XOR bank-swizzle applied on the GLOBAL source slot (both-sides-or-neither).
template<int RPW>
DEV void stage_rows(const u16* __restrict__ g, int gstride, u16* lds, int wave, int lane) {
  const int r_in = lane >> 3, slot = lane & 7;
  const int base_row = wave * RPW;
#pragma unroll
  for (int i = 0; i < RPW / 8; ++i) {
    const int row = base_row + i * 8 + r_in;
    const int sslot = slot ^ (row & 7);
    gl2lds16(g + (size_t)row * gstride + sslot * 8,
             lds + (size_t)(base_row + i * 8) * 64);
  }
}

// Read an 8-bf16 slot (16B) from the swizzled [rows][64] tile.
DEV bf16x8 frag_read(const u16* lds, int row, int kslot) {
  const int slot = kslot ^ (row & 7);
  return *(const bf16x8*)(lds + row * 64 + slot * 8);
}

DEV f32x4 mfma16(bf16x8 a, bf16x8 b, f32x4 c) {
  return __builtin_amdgcn_mfma_f32_16x16x32_bf16(a, b, c, 0, 0, 0);
}
DEV f32x16 mfma32(bf16x8 a, bf16x8 b, f32x16 c) {
  return __builtin_amdgcn_mfma_f32_32x32x16_bf16(a, b, c, 0, 0, 0);
}

// ---------------------------------------------------------------------------
// Weights fp32 -> bf16. grid (256, 4), block 256. dst: [Wq][Wk][Wv][Wo].
__global__ __launch_bounds__(256) void convert_w(
    const float* __restrict__ w0, const float* __restrict__ w1,
    const float* __restrict__ w2, const float* __restrict__ w3,
    u16* __restrict__ dst) {
  const float* src = (blockIdx.y == 0) ? w0 : (blockIdx.y == 1) ? w1
                   : (blockIdx.y == 2) ? w2 : w3;
  const size_t base = (size_t)blockIdx.y * 262144;
  const int i = (blockIdx.x * 256 + threadIdx.x) * 4;
  f32x4 v = *(const f32x4*)(src + i);
  u16x4 o;
  o.x = f2bf(v.x); o.y = f2bf(v.y); o.z = f2bf(v.z); o.w = f2bf(v.w);
  *(u16x4*)(dst + base + i) = o;
}

// ---------------------------------------------------------------------------
// x (B,C,H,W) -> Xp bf16 (B*S, D), adding 2D positional encoding.
// Xp doubles as the residual (read back as bf16 in gemm_out).
__global__ __launch_bounds__(256) void prep_x(
    const float* __restrict__ x, u16* __restrict__ Xp) {
  __shared__ float tile[32][33];
  const int b = blockIdx.z, c0 = blockIdx.y * 32, s0 = blockIdx.x * 32;
  const int t = threadIdx.x;
  const int cf = t >> 5, sf = t & 31;
#pragma unroll
  for (int i = 0; i < 4; ++i) {
    const int c = c0 + cf + i * 8;
    tile[cf + i * 8][sf] = x[((size_t)b * 512 + c) * 1024 + s0 + sf];
  }
  __syncthreads();
  const int cl = t & 31, sl = t >> 5;
  const int cg = c0 + cl;
  const int j = cg >> 2;
  const float dv = expf((float)j * (-9.210340371976184f / 256.0f));
#pragma unroll
  for (int i = 0; i < 4; ++i) {
    const int s = s0 + sl + i * 8;
    const float pos = (cg & 2) ? (float)(s & 31) : (float)(s >> 5);
    const float arg = pos * dv;
    const float pe = (cg & 1) ? cosf(arg) : sinf(arg);
    const float v = tile[cl][sl + i * 8] + pe;
    Xp[((size_t)b * 1024 + s) * 512 + cg] = f2bf(v);
  }
}

// ---------------------------------------------------------------------------
// Fused QKV GEMM: C[8192,1536] = Xp @ [Wq;Wk;Wv]^T, K=512, 128x128 tiles,
// grid (12, 64). Epilogue routes by column region:
//   cols [0,512)     -> Qb row-major, scaled by qscale (1/sqrt(dk)*log2 e)
//   cols [512,1024)  -> Kf: mfma32-A FRAGMENT layout (1KB frags)
//   cols [1024,1536) -> Vf: V^T in the same fragment layout
// Fragment fi = ((b*8+h)*16 + kt)*8 + c*2 + rh; lane(ql,hl) of frag holds
//   K[kt*64+rh*32+ql][h*64+c*16+hl*8..+8]  (resp. Vt[h*64+rh*32+ql][kt*64+...]).
__global__ __launch_bounds__(256) void gemm_qkv(
    const u16* __restrict__ Xp, const u16* __restrict__ Wb,
    u16* __restrict__ Qb, u16* __restrict__ Kf, u16* __restrict__ Vf,
    float qscale) {
  __shared__ __align__(16) u16 smem[128 * 132];   // 33,792 B
  u16* As = smem;
  u16* Bs = smem + 128 * 64;
  const int t = threadIdx.x, lane = t & 63, wave = t >> 6;
  const int bn0 = blockIdx.x * 128, bm0 = blockIdx.y * 128;
  const int wr = wave >> 1, wc = wave & 1;
  const u16* Ag = Xp + (size_t)bm0 * 512;
  const u16* Bg = Wb + (size_t)bn0 * 512;
  f32x4 acc[4][4] = {};
  for (int kt = 0; kt < 512; kt += 64) {
    __syncthreads();
    stage_rows<32>(Ag + kt, 512, As, wave, lane);
    stage_rows<32>(Bg + kt, 512, Bs, wave, lane);
    __syncthreads();
#pragma unroll
    for (int ks = 0; ks < 2; ++ks) {
      bf16x8 af[4], bfr[4];
#pragma unroll
      for (int m = 0; m < 4; ++m)
        af[m] = frag_read(As, wr * 64 + m * 16 + (lane & 15), ks * 4 + (lane >> 4));
#pragma unroll
      for (int n = 0; n < 4; ++n)
        bfr[n] = frag_read(Bs, wc * 64 + n * 16 + (lane & 15), ks * 4 + (lane >> 4));
#pragma unroll
      for (int m = 0; m < 4; ++m)
#pragma unroll
        for (int n = 0; n < 4; ++n)
          acc[m][n] = mfma16(af[m], bfr[n], acc[m][n]);
    }
  }
  const int cl = lane & 15, rg = (lane >> 4) * 4;
  if (bn0 < 512) {
    // ---- Q: row-major, scaled
#pragma unroll
    for (int m = 0; m < 4; ++m)
#pragma unroll
      for (int n = 0; n < 4; ++n) {
        const int col = bn0 + wc * 64 + n * 16 + cl;
#pragma unroll
        for (int r = 0; r < 4; ++r) {
          const int row = bm0 + wr * 64 + m * 16 + rg + r;
          Qb[(size_t)row * 512 + col] = f2bf(acc[m][n][r] * qscale);
        }
      }
  } else {
    const bool isK = (bn0 < 1024);
    __syncthreads();   // staging reads done before LDS overwrite
    if (isK) {
      // stage C tile naturally: smem[seq_local][d_local], stride 132
#pragma unroll
      for (int m = 0; m < 4; ++m)
#pragma unroll
        for (int n = 0; n < 4; ++n) {
          const int col = wc * 64 + n * 16 + cl;
#pragma unroll
          for (int r = 0; r < 4; ++r) {
            const int row = wr * 64 + m * 16 + rg + r;
            smem[row * 132 + col] = f2bf(acc[m][n][r]);
          }
        }
    } else {
      // stage transposed: smem[d_local][seq_local], stride 132
#pragma unroll
      for (int m = 0; m < 4; ++m)
#pragma unroll
        for (int n = 0; n < 4; ++n) {
          const int dvL = wc * 64 + n * 16 + cl;
          const int rowL0 = wr * 64 + m * 16 + rg;
          u16x4 pk;
#pragma unroll
          for (int r = 0; r < 4; ++r) pk[r] = f2bf(acc[m][n][r]);
          *(u16x4*)(smem + dvL * 132 + rowL0) = pk;
        }
    }
    __syncthreads();
    // ---- fragment stores: 32 frags of 1KB, 8 passes x 4 waves
    const int b = bm0 >> 10;
    const int s0 = bm0 & 1023;
    const int hbase = isK ? ((bn0 - 512) >> 6) : ((bn0 - 1024) >> 6);
    u16* dstb = isK ? Kf : Vf;
    const int ql = lane & 31, hl = lane >> 5;
#pragma unroll
    for (int pass = 0; pass < 8; ++pass) {
      const int fidx = pass * 4 + wave;
      const int rh = fidx & 1;
      const int c = (fidx >> 1) & 3;
      const int head_local = (fidx >> 3) & 1;
      const int kt_local = (fidx >> 4) & 1;
      int row_l, col_l;
      if (isK) { row_l = kt_local * 64 + rh * 32 + ql; col_l = head_local * 64 + c * 16 + hl * 8; }
      else     { row_l = head_local * 64 + rh * 32 + ql; col_l = kt_local * 64 + c * 16 + hl * 8; }
      const u16x4 lo = *(const u16x4*)(smem + row_l * 132 + col_l);
      const u16x4 hi = *(const u16x4*)(smem + row_l * 132 + col_l + 4);
      const int h = hbase + head_local;
      const int ktg = (s0 >> 6) + kt_local;
      const size_t fi = (size_t)(((b * 8 + h) * 16 + ktg) * 8 + c * 2 + rh);
      u16* dst = dstb + fi * 512 + lane * 8;
      *(u16x4*)(dst) = lo;
      *(u16x4*)(dst + 4) = hi;
    }
  }
}

// ---------------------------------------------------------------------------
// Out-proj GEMM: ypre16[8192,512] (bf16) = Ob @ Wo^T + bo + resid(bf16 Xp).
// 128x64 tiles, grid (8, 64) = 512 blocks.
__global__ __launch_bounds__(256) void gemm_out(
    const u16* __restrict__ A, const u16* __restrict__ Bt,
    u16* __restrict__ ypre16, const float* __restrict__ bias,
    const u16* __restrict__ residb) {
  __shared__ __align__(16) u16 As[128 * 64];
  __shared__ __align__(16) u16 Bs[64 * 64];
  const int t = threadIdx.x, lane = t & 63, wave = t >> 6;
  const int bn0 = blockIdx.x * 64, bm0 = blockIdx.y * 128;
  const int wr = wave >> 1, wc = wave & 1;
  const u16* Ag = A + (size_t)bm0 * 512;
  const u16* Bg = Bt + (size_t)bn0 * 512;
  f32x4 acc[4][2] = {};
  for (int kt = 0; kt < 512; kt += 64) {
    __syncthreads();
    stage_rows<32>(Ag + kt, 512, As, wave, lane);
    stage_rows<16>(Bg + kt, 512, Bs, wave, lane);
    __syncthreads();
#pragma unroll
    for (int ks = 0; ks < 2; ++ks) {
      bf16x8 af[4], bfr[2];
#pragma unroll
      for (int m = 0; m < 4; ++m)
        af[m] = frag_read(As, wr * 64 + m * 16 + (lane & 15), ks * 4 + (lane >> 4));
#pragma unroll
      for (int n = 0; n < 2; ++n)
        bfr[n] = frag_read(Bs, wc * 32 + n * 16 + (lane & 15), ks * 4 + (lane >> 4));
#pragma unroll
      for (int m = 0; m < 4; ++m)
#pragma unroll
        for (int n = 0; n < 2; ++n)
          acc[m][n] = mfma16(af[m], bfr[n], acc[m][n]);
    }
  }
  const int cl = lane & 15, rg = (lane >> 4) * 4;
#pragma unroll
  for (int m = 0; m < 4; ++m)
#pragma unroll
    for (int n = 0; n < 2; ++n) {
      const int col = bn0 + wc * 32 + n * 16 + cl;
#pragma unroll
      for (int r = 0; r < 4; ++r) {
        const int row = bm0 + wr * 64 + m * 16 + rg + r;
        const float v = acc[m][n][r] + bias[col] + bf2f(residb[(size_t)row * 512 + col]);
        ypre16[(size_t)row * 512 + col] = f2bf(v);
      }
    }
}

// ---------------------------------------------------------------------------
// Flash attention v6: BARRIER-FREE. K/V pre-packed in mfma32-A fragment layout
// by gemm_qkv; each wave loads fragments straight global(L2)->VGPR (coalesced
// 16B/lane), zero LDS, zero __syncthreads. Register ping-pong prefetch of K
// (named ka/kb arrays, static indexing), V issued at tile start and consumed
// after softmax. Grid 512 (b=wg&7 XCD-resident), 4 waves x 32 q. 2048 waves
// = exactly 8/CU co-resident, no tail.
__global__ __launch_bounds__(256, 2) void attn(
    const u16* __restrict__ Qb, const u16* __restrict__ Kf,
    const u16* __restrict__ Vf, u16* __restrict__ Ob) {
  const int t = threadIdx.x, lane = t & 63, wave = t >> 6;
  const int wg = blockIdx.x;
  const int b = wg & 7, h = (wg >> 3) & 7, qt = wg >> 6;
  const int ql = lane & 31, hl = lane >> 5;
  const int q0 = qt * 128 + wave * 32;
  // Q B-fragments: B[col=q][k=d]
  bf16x8 bq[4];
  {
    const u16* qrow = Qb + ((size_t)b * 1024 + q0 + ql) * 512 + h * 64 + hl * 8;
#pragma unroll
    for (int c = 0; c < 4; ++c) bq[c] = *(const bf16x8*)(qrow + c * 16);
  }
  const u16* fb = Kf + (size_t)((b * 8 + h) * 16) * 8 * 512;
  const u16* vb = Vf + (size_t)((b * 8 + h) * 16) * 8 * 512;
  f32x16 ot[2] = {};
  float m_run = -1e30f, l_run = 0.f;
  bf16x8 ka[8], kb_[8], va[8];
  // prologue: K tile 0
#pragma unroll
  for (int f = 0; f < 8; ++f)
    ka[f] = *(const bf16x8*)(fb + (size_t)f * 512 + lane * 8);

  auto tile_step = [&](int tt, bf16x8* kc, bf16x8* kn) {
    // issue V[tt] loads (consumed after softmax, ~400cy cover)
#pragma unroll
    for (int f = 0; f < 8; ++f)
      va[f] = *(const bf16x8*)(vb + ((size_t)(tt * 8 + f)) * 512 + lane * 8);
    // issue K[tt+1] loads into the other buffer (used next tile)
    const int tn = (tt + 1) & 15;
#pragma unroll
    for (int f = 0; f < 8; ++f)
      kn[f] = *(const bf16x8*)(fb + ((size_t)(tn * 8 + f)) * 512 + lane * 8);
    // S^T[k][q] = K[k][:] . Q[q][:]
    f32x16 st[2] = {};
#pragma unroll
    for (int c = 0; c < 4; ++c) {
      st[0] = mfma32(kc[2 * c], bq[c], st[0]);
      st[1] = mfma32(kc[2 * c + 1], bq[c], st[1]);
    }
    // online softmax with defer-max (lane owns q=ql; partner lane has other 32 kv)
    float m0[8];
#pragma unroll
    for (int i2 = 0; i2 < 8; ++i2)
      m0[i2] = fmaxf(fmaxf(st[0][i2], st[0][i2 + 8]), fmaxf(st[1][i2], st[1][i2 + 8]));
#pragma unroll
    for (int i2 = 0; i2 < 4; ++i2) m0[i2] = fmaxf(m0[i2], m0[i2 + 4]);
    float mx = fmaxf(fmaxf(m0[0], m0[1]), fmaxf(m0[2], m0[3]));
    mx = fmaxf(mx, __shfl_xor(mx, 32));
    if (!__all(mx <= m_run + 8.f)) {
      const float mn = fmaxf(m_run, mx);
      const float sc = fexp2(m_run - mn);
      m_run = mn; l_run *= sc;
      ot[0] *= sc; ot[1] *= sc;
    }
#pragma unroll
    for (int i2 = 0; i2 < 16; ++i2) {
      st[0][i2] = fexp2(st[0][i2] - m_run);
      st[1][i2] = fexp2(st[1][i2] - m_run);
    }
    float s0[8];
#pragma unroll
    for (int i2 = 0; i2 < 8; ++i2)
      s0[i2] = (st[0][i2] + st[0][i2 + 8]) + (st[1][i2] + st[1][i2 + 8]);
#pragma unroll
    for (int i2 = 0; i2 < 4; ++i2) s0[i2] = s0[i2] + s0[i2 + 4];
    float rs = (s0[0] + s0[1]) + (s0[2] + s0[3]);
    rs += __shfl_xor(rs, 32);
    l_run += rs;
    // pack P -> bf16, redistribute, O^T += V^T P^T
#pragma unroll
    for (int c = 0; c < 4; ++c) {
      const int kf = c >> 1, i0 = (c & 1) * 4;
      u32 w0 = cvt_pk_bf16(st[kf][2 * i0 + 0], st[kf][2 * i0 + 1]);
      u32 w1 = cvt_pk_bf16(st[kf][2 * i0 + 2], st[kf][2 * i0 + 3]);
      u32 w2 = cvt_pk_bf16(st[kf][2 * i0 + 4], st[kf][2 * i0 + 5]);
      u32 w3 = cvt_pk_bf16(st[kf][2 * i0 + 6], st[kf][2 * i0 + 7]);
      perm32swap(w0, w2);
      perm32swap(w1, w3);
      u32x4 wv; wv.x = w0; wv.y = w1; wv.z = w2; wv.w = w3;
      bf16x8 bp = *(bf16x8*)&wv;
      ot[0] = mfma32(va[2 * c], bp, ot[0]);
      ot[1] = mfma32(va[2 * c + 1], bp, ot[1]);
    }
  };
  for (int tp = 0; tp < 8; ++tp) {
    tile_step(2 * tp, ka, kb_);
    tile_step(2 * tp + 1, kb_, ka);
  }
  // ---- write O (packed u16x4: d = df*32 + rq*8 + 4*hl + j)
  const float inv = 1.f / l_run;
  u16* orow = Ob + ((size_t)b * 1024 + q0 + ql) * 512 + h * 64;
#pragma unroll
  for (int df = 0; df < 2; ++df)
#pragma unroll
    for (int rq = 0; rq < 4; ++rq) {
      u16x4 pk;
#pragma unroll
      for (int j = 0; j < 4; ++j) pk[j] = f2bf(ot[df][rq * 4 + j] * inv);
      *(u16x4*)(orow + df * 32 + rq * 8 + 4 * hl) = pk;
    }
}

// ---------------------------------------------------------------------------
// Single-pass LayerNorm over d=512 (bf16 in) + transpose to (B,C,H,W) fp32.
// grid (64 s-tiles of 16, 8 b), block 256.
__global__ __launch_bounds__(256) void ln_out(
    const u16* __restrict__ ypre16, const float* __restrict__ gamma,
    const float* __restrict__ beta, float* __restrict__ out) {
  __shared__ float tile[16 * 513];
  __shared__ float stats[16][2];
  const int b = blockIdx.y, s0 = blockIdx.x * 16;
  const int t = threadIdx.x, lane = t & 63, wave = t >> 6;
  const u16* src = ypre16 + ((size_t)b * 1024 + s0) * 512;
#pragma unroll
  for (int i = 0; i < 8; ++i) {
    const int idx = i * 256 + t;
    const int flat = idx * 4;
    const int row = flat >> 9, col = flat & 511;
    const u16x4 v = *(const u16x4*)(src + flat);
    float* d = tile + row * 513 + col;
    d[0] = bf2f(v.x); d[1] = bf2f(v.y); d[2] = bf2f(v.z); d[3] = bf2f(v.w);
  }
  __syncthreads();
#pragma unroll
  for (int i = 0; i < 4; ++i) {
    const int r = wave * 4 + i;
    float sum = 0.f, sq = 0.f;
#pragma unroll
    for (int k = 0; k < 8; ++k) {
      const float v = tile[r * 513 + lane + 64 * k];
      sum += v; sq += v * v;
    }
#pragma unroll
    for (int off = 32; off >= 1; off >>= 1) {
      sum += __shfl_xor(sum, off);
      sq  += __shfl_xor(sq, off);
    }
    if (lane == 0) {
      const float mean = sum * (1.f / 512.f);
      const float var = sq * (1.f / 512.f) - mean * mean;
      stats[r][0] = mean;
      stats[r][1] = rsqrtf(var + 1e-5f);
    }
  }
  __syncthreads();
  const int sl = t & 15, cg = t >> 4;
  float* outb = out + (size_t)b * 512 * 1024 + s0;
  const float mean = stats[sl][0], rstd = stats[sl][1];
#pragma unroll 4
  for (int i = 0; i < 32; ++i) {
    const int c = i * 16 + cg;
    const float v = (tile[sl * 513 + c] - mean) * rstd;
    outb[(size_t)c * 1024 + sl] = v * gamma[c] + beta[c];
  }
}

// ---------------------------------------------------------------------------
extern "C" void kernel_launch(void* const* d_in, const int* in_sizes, int n_in,
                              void* d_out, int out_size, void* d_ws, size_t ws_size,
                              hipStream_t stream) {
  const float* x     = (const float*)d_in[0];
  const float* Wq    = (const float*)d_in[1];
  const float* Wk    = (const float*)d_in[2];
  const float* Wv    = (const float*)d_in[3];
  const float* Wo    = (const float*)d_in[4];
  const float* bo    = (const float*)d_in[5];
  const float* gamma = (const float*)d_in[6];
  const float* beta  = (const float*)d_in[7];
  char* ws = (char*)d_ws;
  const size_t MB = 1048576;
  u16*   Xp    = (u16*)(ws);             //  8 MB bf16 (8192,512): x + PE (also residual)
  u16*   Wb    = (u16*)(ws + 8 * MB);    //  2 MB bf16 weights [q][k][v][o]
  u16*   Qb    = (u16*)(ws + 10 * MB);   //  8 MB row-major Q (prescaled)
  u16*   Kfr   = (u16*)(ws + 18 * MB);   //  8 MB K in fragment layout
  u16*   Vfr   = (u16*)(ws + 26 * MB);   //  8 MB V^T in fragment layout
  u16*   Ob    = (u16*)(ws + 34 * MB);   //  8 MB attention out
  u16*   ypre  = (u16*)(ws + 42 * MB);   //  8 MB bf16 pre-LN

  convert_w<<<dim3(256, 4), 256, 0, stream>>>(Wq, Wk, Wv, Wo, Wb);
  prep_x<<<dim3(32, 16, 8), 256, 0, stream>>>(x, Xp);
  // fused QKV: Q scaled by (1/sqrt(dk))*log2(e); K/V emitted in fragment layout
  gemm_qkv<<<dim3(12, 64), 256, 0, stream>>>(Xp, Wb, Qb, Kfr, Vfr,
                                             0.125f * 1.44269504088896f);
  attn<<<512, 256, 0, stream>>>(Qb, Kfr, Vfr, Ob);
  gemm_out<<<dim3(8, 64), 256, 0, stream>>>(Ob, Wb + 3 * 262144, ypre, bo, Xp);
  ln_out<<<dim3(64, 8), 256, 0, stream>>>(ypre, gamma, beta, (float*)d_out);
}

// Round 7
// 94.164 us; speedup vs baseline: 1.0704x; 1.0704x over previous
//
#include <hip/hip_runtime.h>
#include <hip/hip_bf16.h>
#include <math.h>

#define DEV static __device__ __forceinline__

typedef unsigned short u16;
typedef unsigned int u32;
typedef __attribute__((ext_vector_type(4))) float f32x4;
typedef __attribute__((ext_vector_type(16))) float f32x16;
typedef __attribute__((ext_vector_type(8))) __bf16 bf16x8;
typedef __attribute__((ext_vector_type(4))) u16 u16x4;
typedef __attribute__((ext_vector_type(4))) u32 u32x4;

// float -> bf16 bits, round-to-nearest-even
DEV u16 f2bf(float f) {
  unsigned u = __float_as_uint(f);
  u += 0x7fffu + ((u >> 16) & 1u);
  return (u16)(u >> 16);
}
DEV float bf2f(u16 x) { return __uint_as_float((u32)x << 16); }

// single-instruction v_exp_f32
DEV float fexp2(float x) { return __builtin_amdgcn_exp2f(x); }

DEV u32 cvt_pk_bf16(float lo, float hi) {
  u32 r;
  asm("v_cvt_pk_bf16_f32 %0, %1, %2" : "=v"(r) : "v"(lo), "v"(hi));
  return r;
}

// v_permlane32_swap_b32: a' = {a.lo, b.lo}, b' = {a.hi, b.hi}
DEV void perm32swap(u32& a, u32& b) {
  asm("v_permlane32_swap_b32 %0, %1" : "+v"(a), "+v"(b));
}

DEV void gl2lds16(const void* g, void* l) {
  __builtin_amdgcn_global_load_lds(
      (const __attribute__((address_space(1))) void*)g,
      (__attribute__((address_space(3))) void*)l, 16, 0, 0);
}

// Stage RPW rows (per wave) x 64 bf16 cols from global into linear LDS [rows][64]
// with XOR bank-swizzle applied on the GLOBAL source slot (both-sides-or-neither).
template<int RPW>
DEV void stage_rows(const u16* __restrict__ g, int gstride, u16* lds, int wave, int lane) {
  const int r_in = lane >> 3, slot = lane & 7;
  const int base_row = wave * RPW;
#pragma unroll
  for (int i = 0; i < RPW / 8; ++i) {
    const int row = base_row + i * 8 + r_in;
    const int sslot = slot ^ (row & 7);
    gl2lds16(g + (size_t)row * gstride + sslot * 8,
             lds + (size_t)(base_row + i * 8) * 64);
  }
}

// Read an 8-bf16 slot (16B) from the swizzled [rows][64] tile.
DEV bf16x8 frag_read(const u16* lds, int row, int kslot) {
  const int slot = kslot ^ (row & 7);
  return *(const bf16x8*)(lds + row * 64 + slot * 8);
}

DEV f32x4 mfma16(bf16x8 a, bf16x8 b, f32x4 c) {
  return __builtin_amdgcn_mfma_f32_16x16x32_bf16(a, b, c, 0, 0, 0);
}
DEV f32x16 mfma32(bf16x8 a, bf16x8 b, f32x16 c) {
  return __builtin_amdgcn_mfma_f32_32x32x16_bf16(a, b, c, 0, 0, 0);
}

// ---------------------------------------------------------------------------
// Weights fp32 -> bf16. grid (256, 4), block 256. dst: [Wq][Wk][Wv][Wo].
__global__ __launch_bounds__(256) void convert_w(
    const float* __restrict__ w0, const float* __restrict__ w1,
    const float* __restrict__ w2, const float* __restrict__ w3,
    u16* __restrict__ dst) {
  const float* src = (blockIdx.y == 0) ? w0 : (blockIdx.y == 1) ? w1
                   : (blockIdx.y == 2) ? w2 : w3;
  const size_t base = (size_t)blockIdx.y * 262144;
  const int i = (blockIdx.x * 256 + threadIdx.x) * 4;
  f32x4 v = *(const f32x4*)(src + i);
  u16x4 o;
  o.x = f2bf(v.x); o.y = f2bf(v.y); o.z = f2bf(v.z); o.w = f2bf(v.w);
  *(u16x4*)(dst + base + i) = o;
}

// ---------------------------------------------------------------------------
// x (B,C,H,W) -> Xp bf16 (B*S, D), adding 2D positional encoding.
// Xp doubles as the residual (read back as bf16 in gemm_ln).
__global__ __launch_bounds__(256) void prep_x(
    const float* __restrict__ x, u16* __restrict__ Xp) {
  __shared__ float tile[32][33];
  const int b = blockIdx.z, c0 = blockIdx.y * 32, s0 = blockIdx.x * 32;
  const int t = threadIdx.x;
  const int cf = t >> 5, sf = t & 31;
#pragma unroll
  for (int i = 0; i < 4; ++i) {
    const int c = c0 + cf + i * 8;
    tile[cf + i * 8][sf] = x[((size_t)b * 512 + c) * 1024 + s0 + sf];
  }
  __syncthreads();
  const int cl = t & 31, sl = t >> 5;
  const int cg = c0 + cl;
  const int j = cg >> 2;
  const float dv = expf((float)j * (-9.210340371976184f / 256.0f));
#pragma unroll
  for (int i = 0; i < 4; ++i) {
    const int s = s0 + sl + i * 8;
    const float pos = (cg & 2) ? (float)(s & 31) : (float)(s >> 5);
    const float arg = pos * dv;
    const float pe = (cg & 1) ? cosf(arg) : sinf(arg);
    const float v = tile[cl][sl + i * 8] + pe;
    Xp[((size_t)b * 1024 + s) * 512 + cg] = f2bf(v);
  }
}

// ---------------------------------------------------------------------------
// Fused QKV GEMM: C[8192,1536] = Xp @ [Wq;Wk;Wv]^T, K=512, 128x128 tiles,
// grid (12, 64) = 768 blocks (3/CU). Epilogue routes by column region:
//   cols [0,512)    -> Qb, scaled by qscale (1/sqrt(dk) * log2 e)
//   cols [512,1024) -> Kb
//   cols [1024,1536)-> Vtb TRANSPOSED (Vtb[d][row]) via LDS transpose +
//                      coalesced u16x4 stores
__global__ __launch_bounds__(256) void gemm_qkv(
    const u16* __restrict__ Xp, const u16* __restrict__ Wb,
    u16* __restrict__ Qb, u16* __restrict__ Kb, u16* __restrict__ Vtb,
    float qscale) {
  __shared__ __align__(16) u16 smem[128 * 132];   // 33,792 B; staging uses 32 KB
  u16* As = smem;
  u16* Bs = smem + 128 * 64;
  const int t = threadIdx.x, lane = t & 63, wave = t >> 6;
  const int bn0 = blockIdx.x * 128, bm0 = blockIdx.y * 128;
  const int wr = wave >> 1, wc = wave & 1;
  const u16* Ag = Xp + (size_t)bm0 * 512;
  const u16* Bg = Wb + (size_t)bn0 * 512;
  f32x4 acc[4][4] = {};
  for (int kt = 0; kt < 512; kt += 64) {
    __syncthreads();
    stage_rows<32>(Ag + kt, 512, As, wave, lane);
    stage_rows<32>(Bg + kt, 512, Bs, wave, lane);
    __syncthreads();
#pragma unroll
    for (int ks = 0; ks < 2; ++ks) {
      bf16x8 af[4], bfr[4];
#pragma unroll
      for (int m = 0; m < 4; ++m)
        af[m] = frag_read(As, wr * 64 + m * 16 + (lane & 15), ks * 4 + (lane >> 4));
#pragma unroll
      for (int n = 0; n < 4; ++n)
        bfr[n] = frag_read(Bs, wc * 64 + n * 16 + (lane & 15), ks * 4 + (lane >> 4));
#pragma unroll
      for (int m = 0; m < 4; ++m)
#pragma unroll
        for (int n = 0; n < 4; ++n)
          acc[m][n] = mfma16(af[m], bfr[n], acc[m][n]);
    }
  }
  const int cl = lane & 15, rg = (lane >> 4) * 4;
  if (bn0 >= 1024) {
    // ---- V region: transpose through LDS, then coalesced stores
    __syncthreads();   // staging reads done before overwrite
#pragma unroll
    for (int m = 0; m < 4; ++m)
#pragma unroll
      for (int n = 0; n < 4; ++n) {
        const int dvL = wc * 64 + n * 16 + cl;
        const int rowL0 = wr * 64 + m * 16 + rg;
        u16x4 pk;
#pragma unroll
        for (int r = 0; r < 4; ++r) pk[r] = f2bf(acc[m][n][r]);
        *(u16x4*)(smem + dvL * 132 + rowL0) = pk;
      }
    __syncthreads();
    const int dvg0 = bn0 - 1024;
#pragma unroll
    for (int i = 0; i < 16; ++i) {
      const int idx = i * 256 + t;          // 4096 u16x4 total
      const int dv = idx >> 5, ch = (idx & 31) * 4;
      const u16x4 v = *(const u16x4*)(smem + dv * 132 + ch);
      *(u16x4*)(Vtb + (size_t)(dvg0 + dv) * 8192 + bm0 + ch) = v;
    }
  } else {
    u16* dst = (bn0 >= 512) ? Kb : Qb;
    const float al = (bn0 >= 512) ? 1.0f : qscale;
    const int cb = (bn0 & 511) + wc * 64;
#pragma unroll
    for (int m = 0; m < 4; ++m)
#pragma unroll
      for (int n = 0; n < 4; ++n) {
        const int col = cb + n * 16 + cl;
#pragma unroll
        for (int r = 0; r < 4; ++r) {
          const int row = bm0 + wr * 64 + m * 16 + rg + r;
          dst[(size_t)row * 512 + col] = f2bf(acc[m][n][r] * al);
        }
      }
  }
}

// ---------------------------------------------------------------------------
// FUSED out-proj + bias + residual + LayerNorm + NCHW transpose.
// out[(b*512+c)*1024+s] = LN_c(Ob@Wo^T + bo + Xp)[s_row] * gamma[c] + beta[c]
// Block = 32 rows x 512 cols (full LN row in-block). Grid 256 (1/CU), 4 waves,
// wave w owns cols [w*128, w*128+128). Wo streamed via LDS (L2-resident).
__global__ __launch_bounds__(256) void gemm_ln(
    const u16* __restrict__ A, const u16* __restrict__ Bt,
    const u16* __restrict__ residb, const float* __restrict__ bias,
    const float* __restrict__ gamma, const float* __restrict__ beta,
    float* __restrict__ out) {
  __shared__ __align__(16) u16 smem[34816];          // As 32x64 | Bs 512x64 = 68KB
  __shared__ float redsum[4][32], redsq[4][32], srow[32][2];
  const int t = threadIdx.x, lane = t & 63, wave = t >> 6;
  const int m0 = blockIdx.x * 32;
  const int b = m0 >> 10, s0 = m0 & 1023;
  u16* As = smem;
  u16* Bs = smem + 2048;
  const u16* Ag = A + (size_t)m0 * 512;
  f32x4 acc[2][8] = {};
  for (int kt = 0; kt < 512; kt += 64) {
    __syncthreads();
    stage_rows<8>(Ag + kt, 512, As, wave, lane);      // 32 rows of A
    stage_rows<128>(Bt + kt, 512, Bs, wave, lane);    // all 512 rows of Wo
    __syncthreads();
#pragma unroll
    for (int ks = 0; ks < 2; ++ks) {
      bf16x8 af[2], bfr[8];
#pragma unroll
      for (int m = 0; m < 2; ++m)
        af[m] = frag_read(As, m * 16 + (lane & 15), ks * 4 + (lane >> 4));
#pragma unroll
      for (int n = 0; n < 8; ++n)
        bfr[n] = frag_read(Bs, wave * 128 + n * 16 + (lane & 15), ks * 4 + (lane >> 4));
#pragma unroll
      for (int m = 0; m < 2; ++m)
#pragma unroll
        for (int n = 0; n < 8; ++n)
          acc[m][n] = mfma16(af[m], bfr[n], acc[m][n]);
    }
  }
  // ---- epilogue: bias + resid, partial LN stats, stage to LDS (transposed)
  __syncthreads();                 // done reading staging LDS; reuse as float
  float* fsm = (float*)smem;       // per wave: [128 cols][33 rows]
  float* fw = fsm + wave * (128 * 33);
  const int cl = lane & 15, rg = (lane >> 4) * 4;
  float psum[8], psq[8];
#pragma unroll
  for (int i = 0; i < 8; ++i) { psum[i] = 0.f; psq[i] = 0.f; }
#pragma unroll
  for (int m = 0; m < 2; ++m)
#pragma unroll
    for (int n = 0; n < 8; ++n) {
      const int col_l = n * 16 + cl;
      const int col = wave * 128 + col_l;
      const float bi = bias[col];
#pragma unroll
      for (int r = 0; r < 4; ++r) {
        const int row_l = m * 16 + rg + r;
        const float v = acc[m][n][r] + bi
                      + bf2f(residb[(size_t)(m0 + row_l) * 512 + col]);
        fw[col_l * 33 + row_l] = v;
        psum[m * 4 + r] += v;
        psq[m * 4 + r] += v * v;
      }
    }
#pragma unroll
  for (int i = 0; i < 8; ++i) {
#pragma unroll
    for (int off = 8; off >= 1; off >>= 1) {
      psum[i] += __shfl_xor(psum[i], off);
      psq[i]  += __shfl_xor(psq[i], off);
    }
  }
  if (cl == 0) {
#pragma unroll
    for (int m = 0; m < 2; ++m)
#pragma unroll
      for (int r = 0; r < 4; ++r) {
        const int row_l = m * 16 + rg + r;
        redsum[wave][row_l] = psum[m * 4 + r];
        redsq[wave][row_l]  = psq[m * 4 + r];
      }
  }
  __syncthreads();
  if (t < 32) {
    float s = redsum[0][t] + redsum[1][t] + redsum[2][t] + redsum[3][t];
    float q = redsq[0][t] + redsq[1][t] + redsq[2][t] + redsq[3][t];
    const float mean = s * (1.f / 512.f);
    const float var = q * (1.f / 512.f) - mean * mean;
    srow[t][0] = mean;
    srow[t][1] = rsqrtf(var + 1e-5f);
  }
  __syncthreads();
  // ---- normalize + transposed write (contiguous 128B per channel)
  const int row = lane & 31, chalf = lane >> 5;
  const float mean = srow[row][0], rstd = srow[row][1];
  float* outb = out + (size_t)b * 512 * 1024 + s0 + row;
#pragma unroll 4
  for (int cc = 0; cc < 64; ++cc) {
    const int col_l = cc * 2 + chalf;
    const int col = wave * 128 + col_l;
    const float v = (fw[col_l * 33 + row] - mean) * rstd;
    outb[(size_t)col * 1024] = v * gamma[col] + beta[col];
  }
}

// ---------------------------------------------------------------------------
// Flash attention v5 (r5 best-known): split-K across wave pairs + merge.
// Grid 1024; wg -> b = wg&7 (XCD-resident K/V), h = (wg>>3)&7, qt = wg>>6.
// Block = 4 waves: qsub = wave&1 (32 q-rows), half = wave>>1 (kv tiles
// half*8 .. half*8+7). Single-buffered K/V per half (32KB LDS).
// Swapped-operand 32x32x16 MFMA, in-register softmax (v_exp_f32, Q prescaled
// by log2e/sqrt(dk)), cvt_pk + permlane32_swap, defer-max, setprio.
__global__ __launch_bounds__(256, 4) void attn(
    const u16* __restrict__ Qb, const u16* __restrict__ Kb,
    const u16* __restrict__ Vt, u16* __restrict__ Ob) {
  __shared__ __align__(16) u16 Ks[2][64 * 64];
  __shared__ __align__(16) u16 Vs[2][64 * 64];
  const int t = threadIdx.x, lane = t & 63, wave = t >> 6;
  const int wg = blockIdx.x;
  const int b = wg & 7, h = (wg >> 3) & 7, qt = wg >> 6;
  const int qsub = wave & 1, half = wave >> 1;
  const int ql = lane & 31, hl = lane >> 5;
  const int q0 = qt * 64 + qsub * 32;
  bf16x8 bq[4];
  {
    const u16* qrow = Qb + ((size_t)b * 1024 + q0 + ql) * 512 + h * 64 + hl * 8;
#pragma unroll
    for (int c = 0; c < 4; ++c) bq[c] = *(const bf16x8*)(qrow + c * 16);
  }
  f32x16 ot[2] = {};
  float m_run = -1e30f, l_run = 0.f;
  u16* stg_dst = qsub ? Vs[half] : Ks[half];
  for (int i = 0; i < 8; ++i) {
    const int kb = half * 512 + i * 64;
    {
      const int r_in = lane >> 3, slot = lane & 7;
      const u16* src; size_t gs;
      if (qsub) { src = Vt + (size_t)(h * 64) * 8192 + (size_t)b * 1024 + kb; gs = 8192; }
      else      { src = Kb + ((size_t)b * 1024 + kb) * 512 + h * 64;          gs = 512; }
#pragma unroll
      for (int j = 0; j < 8; ++j) {
        const int row = j * 8 + r_in;
        const int ss = slot ^ (row & 7);
        gl2lds16(src + (size_t)row * gs + ss * 8, stg_dst + j * 512);
      }
    }
    __syncthreads();
    f32x16 st[2] = {};
    __builtin_amdgcn_s_setprio(1);
#pragma unroll
    for (int c = 0; c < 4; ++c) {
      bf16x8 a0 = frag_read(Ks[half], ql, c * 2 + hl);
      bf16x8 a1 = frag_read(Ks[half], 32 + ql, c * 2 + hl);
      st[0] = mfma32(a0, bq[c], st[0]);
      st[1] = mfma32(a1, bq[c], st[1]);
    }
    __builtin_amdgcn_s_setprio(0);
    float m0[8];
#pragma unroll
    for (int i2 = 0; i2 < 8; ++i2)
      m0[i2] = fmaxf(fmaxf(st[0][i2], st[0][i2 + 8]), fmaxf(st[1][i2], st[1][i2 + 8]));
#pragma unroll
    for (int i2 = 0; i2 < 4; ++i2) m0[i2] = fmaxf(m0[i2], m0[i2 + 4]);
    float mx = fmaxf(fmaxf(m0[0], m0[1]), fmaxf(m0[2], m0[3]));
    mx = fmaxf(mx, __shfl_xor(mx, 32));
    if (!__all(mx <= m_run + 8.f)) {
      const float mn = fmaxf(m_run, mx);
      const float sc = fexp2(m_run - mn);
      m_run = mn;
      l_run *= sc;
      ot[0] *= sc;
      ot[1] *= sc;
    }
#pragma unroll
    for (int i2 = 0; i2 < 16; ++i2) {
      st[0][i2] = fexp2(st[0][i2] - m_run);
      st[1][i2] = fexp2(st[1][i2] - m_run);
    }
    float s0[8];
#pragma unroll
    for (int i2 = 0; i2 < 8; ++i2)
      s0[i2] = (st[0][i2] + st[0][i2 + 8]) + (st[1][i2] + st[1][i2 + 8]);
#pragma unroll
    for (int i2 = 0; i2 < 4; ++i2) s0[i2] = s0[i2] + s0[i2 + 4];
    float rs = (s0[0] + s0[1]) + (s0[2] + s0[3]);
    rs += __shfl_xor(rs, 32);
    l_run += rs;
    __builtin_amdgcn_s_setprio(1);
#pragma unroll
    for (int c = 0; c < 4; ++c) {
      const int kf = c >> 1, i0 = (c & 1) * 4;
      u32 w0 = cvt_pk_bf16(st[kf][2 * i0 + 0], st[kf][2 * i0 + 1]);
      u32 w1 = cvt_pk_bf16(st[kf][2 * i0 + 2], st[kf][2 * i0 + 3]);
      u32 w2 = cvt_pk_bf16(st[kf][2 * i0 + 4], st[kf][2 * i0 + 5]);
      u32 w3 = cvt_pk_bf16(st[kf][2 * i0 + 6], st[kf][2 * i0 + 7]);
      perm32swap(w0, w2);
      perm32swap(w1, w3);
      u32x4 wv; wv.x = w0; wv.y = w1; wv.z = w2; wv.w = w3;
      bf16x8 bp = *(bf16x8*)&wv;
      bf16x8 v0 = frag_read(Vs[half], ql, c * 2 + hl);
      bf16x8 v1 = frag_read(Vs[half], 32 + ql, c * 2 + hl);
      ot[0] = mfma32(v0, bp, ot[0]);
      ot[1] = mfma32(v1, bp, ot[1]);
    }
    __builtin_amdgcn_s_setprio(0);
    __syncthreads();
  }
  float* Om = (float*)&Ks[0][0] + qsub * 2048;
  float* Ml = (float*)&Vs[0][0];
  if (wave >= 2) {
#pragma unroll
    for (int df = 0; df < 2; ++df)
#pragma unroll
      for (int r = 0; r < 16; ++r) {
        const int dr = (r & 3) + 8 * (r >> 2) + 4 * hl;
        Om[(df * 32 + dr) * 32 + ql] = ot[df][r];
      }
    if (hl == 0) {
      Ml[qsub * 64 + ql] = m_run;
      Ml[qsub * 64 + 32 + ql] = l_run;
    }
    __syncthreads();
  } else {
    __syncthreads();
    const float m2 = Ml[qsub * 64 + ql];
    const float l2 = Ml[qsub * 64 + 32 + ql];
    const float m = fmaxf(m_run, m2);
    const float a = fexp2(m_run - m);
    const float bsc = fexp2(m2 - m);
    const float inv = 1.f / (l_run * a + l2 * bsc);
    u16* orow = Ob + ((size_t)b * 1024 + q0 + ql) * 512 + h * 64;
#pragma unroll
    for (int df = 0; df < 2; ++df)
#pragma unroll
      for (int r = 0; r < 16; ++r) {
        const int dr = (r & 3) + 8 * (r >> 2) + 4 * hl;
        const float v = ot[df][r] * a + Om[(df * 32 + dr) * 32 + ql] * bsc;
        orow[df * 32 + dr] = f2bf(v * inv);
      }
  }
}

// ---------------------------------------------------------------------------
extern "C" void kernel_launch(void* const* d_in, const int* in_sizes, int n_in,
                              void* d_out, int out_size, void* d_ws, size_t ws_size,
                              hipStream_t stream) {
  const float* x     = (const float*)d_in[0];
  const float* Wq    = (const float*)d_in[1];
  const float* Wk    = (const float*)d_in[2];
  const float* Wv    = (const float*)d_in[3];
  const float* Wo    = (const float*)d_in[4];
  const float* bo    = (const float*)d_in[5];
  const float* gamma = (const float*)d_in[6];
  const float* beta  = (const float*)d_in[7];
  char* ws = (char*)d_ws;
  const size_t MB = 1048576;
  u16*   Xp    = (u16*)(ws);             //  8 MB bf16 (8192,512): x + PE (also residual)
  u16*   Wb    = (u16*)(ws + 8 * MB);    //  2 MB bf16 weights [q][k][v][o]
  u16*   Qb    = (u16*)(ws + 10 * MB);   //  8 MB (prescaled)
  u16*   Kb    = (u16*)(ws + 18 * MB);   //  8 MB
  u16*   Vtb   = (u16*)(ws + 26 * MB);   //  8 MB bf16 V^T (512, 8192)
  u16*   Ob    = (u16*)(ws + 34 * MB);   //  8 MB attention out

  convert_w<<<dim3(256, 4), 256, 0, stream>>>(Wq, Wk, Wv, Wo, Wb);
  prep_x<<<dim3(32, 16, 8), 256, 0, stream>>>(x, Xp);
  // fused QKV: Q scaled by (1/sqrt(dk))*log2(e); V written transposed
  gemm_qkv<<<dim3(12, 64), 256, 0, stream>>>(Xp, Wb, Qb, Kb, Vtb,
                                             0.125f * 1.44269504088896f);
  attn<<<1024, 256, 0, stream>>>(Qb, Kb, Vtb, Ob);
  // fused out-proj + bias + residual + LayerNorm + NCHW transpose
  gemm_ln<<<256, 256, 0, stream>>>(Ob, Wb + 3 * 262144, Xp, bo, gamma, beta,
                                   (float*)d_out);
}

// Round 8
// 94.091 us; speedup vs baseline: 1.0712x; 1.0008x over previous
//
#include <hip/hip_runtime.h>
#include <hip/hip_bf16.h>
#include <math.h>

#define DEV static __device__ __forceinline__

typedef unsigned short u16;
typedef unsigned int u32;
typedef __attribute__((ext_vector_type(4))) float f32x4;
typedef __attribute__((ext_vector_type(16))) float f32x16;
typedef __attribute__((ext_vector_type(8))) __bf16 bf16x8;
typedef __attribute__((ext_vector_type(4))) u16 u16x4;
typedef __attribute__((ext_vector_type(4))) u32 u32x4;

// float -> bf16 bits, round-to-nearest-even
DEV u16 f2bf(float f) {
  unsigned u = __float_as_uint(f);
  u += 0x7fffu + ((u >> 16) & 1u);
  return (u16)(u >> 16);
}
DEV float bf2f(u16 x) { return __uint_as_float((u32)x << 16); }

// single-instruction v_exp_f32
DEV float fexp2(float x) { return __builtin_amdgcn_exp2f(x); }

DEV u32 cvt_pk_bf16(float lo, float hi) {
  u32 r;
  asm("v_cvt_pk_bf16_f32 %0, %1, %2" : "=v"(r) : "v"(lo), "v"(hi));
  return r;
}

// v_permlane32_swap_b32: a' = {a.lo, b.lo}, b' = {a.hi, b.hi}
DEV void perm32swap(u32& a, u32& b) {
  asm("v_permlane32_swap_b32 %0, %1" : "+v"(a), "+v"(b));
}

DEV void gl2lds16(const void* g, void* l) {
  __builtin_amdgcn_global_load_lds(
      (const __attribute__((address_space(1))) void*)g,
      (__attribute__((address_space(3))) void*)l, 16, 0, 0);
}

// Stage RPW rows (per wave) x 64 bf16 cols from global into linear LDS [rows][64]
// with XOR bank-swizzle applied on the GLOBAL source slot (both-sides-or-neither).
template<int RPW>
DEV void stage_rows(const u16* __restrict__ g, int gstride, u16* lds, int wave, int lane) {
  const int r_in = lane >> 3, slot = lane & 7;
  const int base_row = wave * RPW;
#pragma unroll
  for (int i = 0; i < RPW / 8; ++i) {
    const int row = base_row + i * 8 + r_in;
    const int sslot = slot ^ (row & 7);
    gl2lds16(g + (size_t)row * gstride + sslot * 8,
             lds + (size_t)(base_row + i * 8) * 64);
  }
}

// Read an 8-bf16 slot (16B) from the swizzled [rows][64] tile.
DEV bf16x8 frag_read(const u16* lds, int row, int kslot) {
  const int slot = kslot ^ (row & 7);
  return *(const bf16x8*)(lds + row * 64 + slot * 8);
}

DEV f32x4 mfma16(bf16x8 a, bf16x8 b, f32x4 c) {
  return __builtin_amdgcn_mfma_f32_16x16x32_bf16(a, b, c, 0, 0, 0);
}
DEV f32x16 mfma32(bf16x8 a, bf16x8 b, f32x16 c) {
  return __builtin_amdgcn_mfma_f32_32x32x16_bf16(a, b, c, 0, 0, 0);
}

// ---------------------------------------------------------------------------
// Pack weights fp32 -> bf16 MFMA B-fragment layout.
// Fragment (c16, kchunk): lane(cl=lane&15, ko=lane>>4) holds
//   W[c16*16+cl][kchunk*32 + ko*8 .. +8]  -> pack[(c16*16+kchunk)*512 + lane*8]
// grid (128, 4): c16 = bx>>2, kchunk = (bx&3)*4 + wave; by = weight {q,k,v,o}.
__global__ __launch_bounds__(256) void pack_w(
    const float* __restrict__ w0, const float* __restrict__ w1,
    const float* __restrict__ w2, const float* __restrict__ w3,
    u16* __restrict__ dst) {
  const float* src = (blockIdx.y == 0) ? w0 : (blockIdx.y == 1) ? w1
                   : (blockIdx.y == 2) ? w2 : w3;
  const int lane = threadIdx.x & 63, wave = threadIdx.x >> 6;
  const int c16 = blockIdx.x >> 2;
  const int kchunk = (blockIdx.x & 3) * 4 + wave;
  const int cl = lane & 15, ko = lane >> 4;
  const float* s = src + (size_t)(c16 * 16 + cl) * 512 + kchunk * 32 + ko * 8;
  const f32x4 a = *(const f32x4*)(s);
  const f32x4 b = *(const f32x4*)(s + 4);
  u16x4 lo, hi;
#pragma unroll
  for (int j = 0; j < 4; ++j) { lo[j] = f2bf(a[j]); hi[j] = f2bf(b[j]); }
  u16* d = dst + (size_t)blockIdx.y * 262144
               + (size_t)(c16 * 16 + kchunk) * 512 + lane * 8;
  *(u16x4*)(d) = lo;
  *(u16x4*)(d + 4) = hi;
}

// ---------------------------------------------------------------------------
// x (B,C,H,W) -> Xp bf16 (B*S, D), adding 2D positional encoding.
// Xp doubles as the residual (read back as bf16 in gemm_ln).
__global__ __launch_bounds__(256) void prep_x(
    const float* __restrict__ x, u16* __restrict__ Xp) {
  __shared__ float tile[32][33];
  const int b = blockIdx.z, c0 = blockIdx.y * 32, s0 = blockIdx.x * 32;
  const int t = threadIdx.x;
  const int cf = t >> 5, sf = t & 31;
#pragma unroll
  for (int i = 0; i < 4; ++i) {
    const int c = c0 + cf + i * 8;
    tile[cf + i * 8][sf] = x[((size_t)b * 512 + c) * 1024 + s0 + sf];
  }
  __syncthreads();
  const int cl = t & 31, sl = t >> 5;
  const int cg = c0 + cl;
  const int j = cg >> 2;
  const float dv = expf((float)j * (-9.210340371976184f / 256.0f));
#pragma unroll
  for (int i = 0; i < 4; ++i) {
    const int s = s0 + sl + i * 8;
    const float pos = (cg & 2) ? (float)(s & 31) : (float)(s >> 5);
    const float arg = pos * dv;
    const float pe = (cg & 1) ? cosf(arg) : sinf(arg);
    const float v = tile[cl][sl + i * 8] + pe;
    Xp[((size_t)b * 1024 + s) * 512 + cg] = f2bf(v);
  }
}

// ---------------------------------------------------------------------------
// Fused QKV GEMM: C[8192,1536] = Xp @ [Wq;Wk;Wv]^T, K=512, 128x128 tiles,
// grid (12, 64) = 768 blocks (3/CU). B operand read DIRECT from packed
// fragments (coalesced global->VGPR, no LDS, no staging barrier on B).
// Epilogue routes by column region: Q (scaled), K row-major, V transposed.
__global__ __launch_bounds__(256) void gemm_qkv(
    const u16* __restrict__ Xp, const u16* __restrict__ Wpk,
    u16* __restrict__ Qb, u16* __restrict__ Kb, u16* __restrict__ Vtb,
    float qscale) {
  __shared__ __align__(16) u16 smem[128 * 132];   // As 128x64 | V-transpose reuse
  u16* As = smem;
  const int t = threadIdx.x, lane = t & 63, wave = t >> 6;
  const int bn0 = blockIdx.x * 128, bm0 = blockIdx.y * 128;
  const int wr = wave >> 1, wc = wave & 1;
  const int colbase = bn0 + wc * 64;
  const int w = colbase >> 9;                     // 0=Wq 1=Wk 2=Wv
  const int cb16 = (colbase & 511) >> 4;          // base c16 within weight
  const u16* Bf = Wpk + (size_t)w * 262144;
  const u16* Ag = Xp + (size_t)bm0 * 512;
  f32x4 acc[4][4] = {};
  for (int kt = 0; kt < 512; kt += 64) {
    __syncthreads();
    stage_rows<32>(Ag + kt, 512, As, wave, lane);
    __syncthreads();
#pragma unroll
    for (int ks = 0; ks < 2; ++ks) {
      const int kc = (kt >> 5) + ks;
      bf16x8 af[4], bfr[4];
#pragma unroll
      for (int n = 0; n < 4; ++n)
        bfr[n] = *(const bf16x8*)(Bf + (size_t)((cb16 + n) * 16 + kc) * 512 + lane * 8);
#pragma unroll
      for (int m = 0; m < 4; ++m)
        af[m] = frag_read(As, wr * 64 + m * 16 + (lane & 15), ks * 4 + (lane >> 4));
#pragma unroll
      for (int m = 0; m < 4; ++m)
#pragma unroll
        for (int n = 0; n < 4; ++n)
          acc[m][n] = mfma16(af[m], bfr[n], acc[m][n]);
    }
  }
  const int cl = lane & 15, rg = (lane >> 4) * 4;
  if (bn0 >= 1024) {
    // ---- V region: transpose through LDS, then coalesced stores
    __syncthreads();   // staging reads done before overwrite
#pragma unroll
    for (int m = 0; m < 4; ++m)
#pragma unroll
      for (int n = 0; n < 4; ++n) {
        const int dvL = wc * 64 + n * 16 + cl;
        const int rowL0 = wr * 64 + m * 16 + rg;
        u16x4 pk;
#pragma unroll
        for (int r = 0; r < 4; ++r) pk[r] = f2bf(acc[m][n][r]);
        *(u16x4*)(smem + dvL * 132 + rowL0) = pk;
      }
    __syncthreads();
    const int dvg0 = bn0 - 1024;
#pragma unroll
    for (int i = 0; i < 16; ++i) {
      const int idx = i * 256 + t;          // 4096 u16x4 total
      const int dv = idx >> 5, ch = (idx & 31) * 4;
      const u16x4 v = *(const u16x4*)(smem + dv * 132 + ch);
      *(u16x4*)(Vtb + (size_t)(dvg0 + dv) * 8192 + bm0 + ch) = v;
    }
  } else {
    u16* dst = (bn0 >= 512) ? Kb : Qb;
    const float al = (bn0 >= 512) ? 1.0f : qscale;
    const int cb = (bn0 & 511) + wc * 64;
#pragma unroll
    for (int m = 0; m < 4; ++m)
#pragma unroll
      for (int n = 0; n < 4; ++n) {
        const int col = cb + n * 16 + cl;
#pragma unroll
        for (int r = 0; r < 4; ++r) {
          const int row = bm0 + wr * 64 + m * 16 + rg + r;
          dst[(size_t)row * 512 + col] = f2bf(acc[m][n][r] * al);
        }
      }
  }
}

// ---------------------------------------------------------------------------
// FUSED out-proj + bias + residual + LayerNorm + NCHW transpose.
// Block = 32 rows x 512 cols, grid 256, 4 waves (wave w owns cols w*128..+128).
// Wo read DIRECT from packed fragments (no B staging, no per-step drain).
__global__ __launch_bounds__(256) void gemm_ln(
    const u16* __restrict__ A, const u16* __restrict__ Wpk,
    const u16* __restrict__ residb, const float* __restrict__ bias,
    const float* __restrict__ gamma, const float* __restrict__ beta,
    float* __restrict__ out) {
  __shared__ __align__(16) u16 smem[34816];          // As 32x64 | fsm reuse (68KB)
  __shared__ float redsum[4][32], redsq[4][32], srow[32][2];
  const int t = threadIdx.x, lane = t & 63, wave = t >> 6;
  const int m0 = blockIdx.x * 32;
  const int b = m0 >> 10, s0 = m0 & 1023;
  u16* As = smem;
  const u16* Bf = Wpk + (size_t)3 * 262144;        // Wo
  const u16* Ag = A + (size_t)m0 * 512;
  f32x4 acc[2][8] = {};
  for (int kt = 0; kt < 512; kt += 64) {
    __syncthreads();
    stage_rows<8>(Ag + kt, 512, As, wave, lane);      // 32 rows of A
    __syncthreads();
#pragma unroll
    for (int ks = 0; ks < 2; ++ks) {
      const int kc = (kt >> 5) + ks;
      bf16x8 af[2], bfr[8];
#pragma unroll
      for (int n = 0; n < 8; ++n)
        bfr[n] = *(const bf16x8*)(Bf + (size_t)((wave * 8 + n) * 16 + kc) * 512 + lane * 8);
#pragma unroll
      for (int m = 0; m < 2; ++m)
        af[m] = frag_read(As, m * 16 + (lane & 15), ks * 4 + (lane >> 4));
#pragma unroll
      for (int m = 0; m < 2; ++m)
#pragma unroll
        for (int n = 0; n < 8; ++n)
          acc[m][n] = mfma16(af[m], bfr[n], acc[m][n]);
    }
  }
  // ---- epilogue: bias + resid, partial LN stats, stage to LDS (transposed)
  __syncthreads();                 // done reading staging LDS; reuse as float
  float* fsm = (float*)smem;       // per wave: [128 cols][33 rows]
  float* fw = fsm + wave * (128 * 33);
  const int cl = lane & 15, rg = (lane >> 4) * 4;
  float psum[8], psq[8];
#pragma unroll
  for (int i = 0; i < 8; ++i) { psum[i] = 0.f; psq[i] = 0.f; }
#pragma unroll
  for (int m = 0; m < 2; ++m)
#pragma unroll
    for (int n = 0; n < 8; ++n) {
      const int col_l = n * 16 + cl;
      const int col = wave * 128 + col_l;
      const float bi = bias[col];
#pragma unroll
      for (int r = 0; r < 4; ++r) {
        const int row_l = m * 16 + rg + r;
        const float v = acc[m][n][r] + bi
                      + bf2f(residb[(size_t)(m0 + row_l) * 512 + col]);
        fw[col_l * 33 + row_l] = v;
        psum[m * 4 + r] += v;
        psq[m * 4 + r] += v * v;
      }
    }
#pragma unroll
  for (int i = 0; i < 8; ++i) {
#pragma unroll
    for (int off = 8; off >= 1; off >>= 1) {
      psum[i] += __shfl_xor(psum[i], off);
      psq[i]  += __shfl_xor(psq[i], off);
    }
  }
  if (cl == 0) {
#pragma unroll
    for (int m = 0; m < 2; ++m)
#pragma unroll
      for (int r = 0; r < 4; ++r) {
        const int row_l = m * 16 + rg + r;
        redsum[wave][row_l] = psum[m * 4 + r];
        redsq[wave][row_l]  = psq[m * 4 + r];
      }
  }
  __syncthreads();
  if (t < 32) {
    float s = redsum[0][t] + redsum[1][t] + redsum[2][t] + redsum[3][t];
    float q = redsq[0][t] + redsq[1][t] + redsq[2][t] + redsq[3][t];
    const float mean = s * (1.f / 512.f);
    const float var = q * (1.f / 512.f) - mean * mean;
    srow[t][0] = mean;
    srow[t][1] = rsqrtf(var + 1e-5f);
  }
  __syncthreads();
  // ---- normalize + transposed write (contiguous 128B per channel)
  const int row = lane & 31, chalf = lane >> 5;
  const float mean = srow[row][0], rstd = srow[row][1];
  float* outb = out + (size_t)b * 512 * 1024 + s0 + row;
#pragma unroll 4
  for (int cc = 0; cc < 64; ++cc) {
    const int col_l = cc * 2 + chalf;
    const int col = wave * 128 + col_l;
    const float v = (fw[col_l * 33 + row] - mean) * rstd;
    outb[(size_t)col * 1024] = v * gamma[col] + beta[col];
  }
}

// ---------------------------------------------------------------------------
// Flash attention v5 (best-known): split-K across wave pairs + merge.
// Grid 1024; wg -> b = wg&7 (XCD-resident K/V), h = (wg>>3)&7, qt = wg>>6.
// Block = 4 waves: qsub = wave&1 (32 q-rows), half = wave>>1 (kv tiles
// half*8 .. half*8+7). Single-buffered K/V per half (32KB LDS).
// Swapped-operand 32x32x16 MFMA, in-register softmax (v_exp_f32, Q prescaled
// by log2e/sqrt(dk)), cvt_pk + permlane32_swap, defer-max, setprio.
__global__ __launch_bounds__(256, 4) void attn(
    const u16* __restrict__ Qb, const u16* __restrict__ Kb,
    const u16* __restrict__ Vt, u16* __restrict__ Ob) {
  __shared__ __align__(16) u16 Ks[2][64 * 64];
  __shared__ __align__(16) u16 Vs[2][64 * 64];
  const int t = threadIdx.x, lane = t & 63, wave = t >> 6;
  const int wg = blockIdx.x;
  const int b = wg & 7, h = (wg >> 3) & 7, qt = wg >> 6;
  const int qsub = wave & 1, half = wave >> 1;
  const int ql = lane & 31, hl = lane >> 5;
  const int q0 = qt * 64 + qsub * 32;
  bf16x8 bq[4];
  {
    const u16* qrow = Qb + ((size_t)b * 1024 + q0 + ql) * 512 + h * 64 + hl * 8;
#pragma unroll
    for (int c = 0; c < 4; ++c) bq[c] = *(const bf16x8*)(qrow + c * 16);
  }
  f32x16 ot[2] = {};
  float m_run = -1e30f, l_run = 0.f;
  u16* stg_dst = qsub ? Vs[half] : Ks[half];
  for (int i = 0; i < 8; ++i) {
    const int kb = half * 512 + i * 64;
    {
      const int r_in = lane >> 3, slot = lane & 7;
      const u16* src; size_t gs;
      if (qsub) { src = Vt + (size_t)(h * 64) * 8192 + (size_t)b * 1024 + kb; gs = 8192; }
      else      { src = Kb + ((size_t)b * 1024 + kb) * 512 + h * 64;          gs = 512; }
#pragma unroll
      for (int j = 0; j < 8; ++j) {
        const int row = j * 8 + r_in;
        const int ss = slot ^ (row & 7);
        gl2lds16(src + (size_t)row * gs + ss * 8, stg_dst + j * 512);
      }
    }
    __syncthreads();
    f32x16 st[2] = {};
    __builtin_amdgcn_s_setprio(1);
#pragma unroll
    for (int c = 0; c < 4; ++c) {
      bf16x8 a0 = frag_read(Ks[half], ql, c * 2 + hl);
      bf16x8 a1 = frag_read(Ks[half], 32 + ql, c * 2 + hl);
      st[0] = mfma32(a0, bq[c], st[0]);
      st[1] = mfma32(a1, bq[c], st[1]);
    }
    __builtin_amdgcn_s_setprio(0);
    float m0[8];
#pragma unroll
    for (int i2 = 0; i2 < 8; ++i2)
      m0[i2] = fmaxf(fmaxf(st[0][i2], st[0][i2 + 8]), fmaxf(st[1][i2], st[1][i2 + 8]));
#pragma unroll
    for (int i2 = 0; i2 < 4; ++i2) m0[i2] = fmaxf(m0[i2], m0[i2 + 4]);
    float mx = fmaxf(fmaxf(m0[0], m0[1]), fmaxf(m0[2], m0[3]));
    mx = fmaxf(mx, __shfl_xor(mx, 32));
    if (!__all(mx <= m_run + 8.f)) {
      const float mn = fmaxf(m_run, mx);
      const float sc = fexp2(m_run - mn);
      m_run = mn;
      l_run *= sc;
      ot[0] *= sc;
      ot[1] *= sc;
    }
#pragma unroll
    for (int i2 = 0; i2 < 16; ++i2) {
      st[0][i2] = fexp2(st[0][i2] - m_run);
      st[1][i2] = fexp2(st[1][i2] - m_run);
    }
    float s0[8];
#pragma unroll
    for (int i2 = 0; i2 < 8; ++i2)
      s0[i2] = (st[0][i2] + st[0][i2 + 8]) + (st[1][i2] + st[1][i2 + 8]);
#pragma unroll
    for (int i2 = 0; i2 < 4; ++i2) s0[i2] = s0[i2] + s0[i2 + 4];
    float rs = (s0[0] + s0[1]) + (s0[2] + s0[3]);
    rs += __shfl_xor(rs, 32);
    l_run += rs;
    __builtin_amdgcn_s_setprio(1);
#pragma unroll
    for (int c = 0; c < 4; ++c) {
      const int kf = c >> 1, i0 = (c & 1) * 4;
      u32 w0 = cvt_pk_bf16(st[kf][2 * i0 + 0], st[kf][2 * i0 + 1]);
      u32 w1 = cvt_pk_bf16(st[kf][2 * i0 + 2], st[kf][2 * i0 + 3]);
      u32 w2 = cvt_pk_bf16(st[kf][2 * i0 + 4], st[kf][2 * i0 + 5]);
      u32 w3 = cvt_pk_bf16(st[kf][2 * i0 + 6], st[kf][2 * i0 + 7]);
      perm32swap(w0, w2);
      perm32swap(w1, w3);
      u32x4 wv; wv.x = w0; wv.y = w1; wv.z = w2; wv.w = w3;
      bf16x8 bp = *(bf16x8*)&wv;
      bf16x8 v0 = frag_read(Vs[half], ql, c * 2 + hl);
      bf16x8 v1 = frag_read(Vs[half], 32 + ql, c * 2 + hl);
      ot[0] = mfma32(v0, bp, ot[0]);
      ot[1] = mfma32(v1, bp, ot[1]);
    }
    __builtin_amdgcn_s_setprio(0);
    __syncthreads();
  }
  float* Om = (float*)&Ks[0][0] + qsub * 2048;
  float* Ml = (float*)&Vs[0][0];
  if (wave >= 2) {
#pragma unroll
    for (int df = 0; df < 2; ++df)
#pragma unroll
      for (int r = 0; r < 16; ++r) {
        const int dr = (r & 3) + 8 * (r >> 2) + 4 * hl;
        Om[(df * 32 + dr) * 32 + ql] = ot[df][r];
      }
    if (hl == 0) {
      Ml[qsub * 64 + ql] = m_run;
      Ml[qsub * 64 + 32 + ql] = l_run;
    }
    __syncthreads();
  } else {
    __syncthreads();
    const float m2 = Ml[qsub * 64 + ql];
    const float l2 = Ml[qsub * 64 + 32 + ql];
    const float m = fmaxf(m_run, m2);
    const float a = fexp2(m_run - m);
    const float bsc = fexp2(m2 - m);
    const float inv = 1.f / (l_run * a + l2 * bsc);
    u16* orow = Ob + ((size_t)b * 1024 + q0 + ql) * 512 + h * 64;
#pragma unroll
    for (int df = 0; df < 2; ++df)
#pragma unroll
      for (int r = 0; r < 16; ++r) {
        const int dr = (r & 3) + 8 * (r >> 2) + 4 * hl;
        const float v = ot[df][r] * a + Om[(df * 32 + dr) * 32 + ql] * bsc;
        orow[df * 32 + dr] = f2bf(v * inv);
      }
  }
}

// ---------------------------------------------------------------------------
extern "C" void kernel_launch(void* const* d_in, const int* in_sizes, int n_in,
                              void* d_out, int out_size, void* d_ws, size_t ws_size,
                              hipStream_t stream) {
  const float* x     = (const float*)d_in[0];
  const float* Wq    = (const float*)d_in[1];
  const float* Wk    = (const float*)d_in[2];
  const float* Wv    = (const float*)d_in[3];
  const float* Wo    = (const float*)d_in[4];
  const float* bo    = (const float*)d_in[5];
  const float* gamma = (const float*)d_in[6];
  const float* beta  = (const float*)d_in[7];
  char* ws = (char*)d_ws;
  const size_t MB = 1048576;
  u16*   Xp    = (u16*)(ws);             //  8 MB bf16 (8192,512): x + PE (also residual)
  u16*   Wpk   = (u16*)(ws + 8 * MB);    //  2 MB packed weight fragments [q][k][v][o]
  u16*   Qb    = (u16*)(ws + 10 * MB);   //  8 MB (prescaled)
  u16*   Kb    = (u16*)(ws + 18 * MB);   //  8 MB
  u16*   Vtb   = (u16*)(ws + 26 * MB);   //  8 MB bf16 V^T (512, 8192)
  u16*   Ob    = (u16*)(ws + 34 * MB);   //  8 MB attention out

  pack_w<<<dim3(128, 4), 256, 0, stream>>>(Wq, Wk, Wv, Wo, Wpk);
  prep_x<<<dim3(32, 16, 8), 256, 0, stream>>>(x, Xp);
  // fused QKV: Q scaled by (1/sqrt(dk))*log2(e); V written transposed
  gemm_qkv<<<dim3(12, 64), 256, 0, stream>>>(Xp, Wpk, Qb, Kb, Vtb,
                                             0.125f * 1.44269504088896f);
  attn<<<1024, 256, 0, stream>>>(Qb, Kb, Vtb, Ob);
  // fused out-proj + bias + residual + LayerNorm + NCHW transpose
  gemm_ln<<<256, 256, 0, stream>>>(Ob, Wpk, Xp, bo, gamma, beta,
                                   (float*)d_out);
}